// Round 9
// baseline (180.742 us; speedup 1.0000x reference)
//
#include <hip/hip_runtime.h>

typedef float f32x4 __attribute__((ext_vector_type(4)));
typedef __bf16 bf16x8 __attribute__((ext_vector_type(8)));
typedef unsigned short u16;

#define DEVFN __device__ __forceinline__

DEVFN u16 f2bf(float f) {
    unsigned u = __builtin_bit_cast(unsigned, f);
    u += 0x7fffu + ((u >> 16) & 1u);
    return (u16)(u >> 16);
}
DEVFN float bf2f(u16 h) {
    unsigned u = ((unsigned)h) << 16;
    return __builtin_bit_cast(float, u);
}

DEVFN void gl2lds16(const void* g, void* l) {
    __builtin_amdgcn_global_load_lds(
        (const __attribute__((address_space(1))) void*)g,
        (__attribute__((address_space(3))) void*)l, 16, 0, 0);
}

// =============== shared 128x128 NT MFMA core (tile 128x128, K-step 64) ===============
DEVFN void gemm_core128(const u16* __restrict__ Ab, int lda,
                        const u16* __restrict__ Bb, int ldb, int K,
                        u16* As, u16* Bs, f32x4 (&acc)[4][4], int tid) {
    const int wv = tid >> 6, ln = tid & 63;
    const int wm = (wv >> 1) * 64, wn = (wv & 1) * 64;
    for (int k0 = 0; k0 < K; k0 += 64) {
        #pragma unroll
        for (int i = 0; i < 4; i++) {
            int c = i * 256 + tid;
            int row = c >> 3, kp = (c & 7) * 8;
            gl2lds16(Ab + (long)row * lda + k0 + kp, &As[(i * 256 + wv * 64) * 8]);
        }
        #pragma unroll
        for (int i = 0; i < 4; i++) {
            int c = i * 256 + tid;
            int row = c >> 3, kp = (c & 7) * 8;
            gl2lds16(Bb + (long)row * ldb + k0 + kp, &Bs[(i * 256 + wv * 64) * 8]);
        }
        __syncthreads();
        #pragma unroll
        for (int kk = 0; kk < 2; kk++) {
            bf16x8 af[4], bfr[4];
            const int rr = ln & 15, ks = kk * 32 + (ln >> 4) * 8;
            #pragma unroll
            for (int m = 0; m < 4; m++) af[m] = *(const bf16x8*)&As[(wm + m * 16 + rr) * 64 + ks];
            #pragma unroll
            for (int n = 0; n < 4; n++) bfr[n] = *(const bf16x8*)&Bs[(wn + n * 16 + rr) * 64 + ks];
            #pragma unroll
            for (int m = 0; m < 4; m++)
                #pragma unroll
                for (int n = 0; n < 4; n++)
                    acc[m][n] = __builtin_amdgcn_mfma_f32_16x16x32_bf16(af[m], bfr[n], acc[m][n], 0, 0, 0);
        }
        __syncthreads();
    }
}

// =============== weights convert + DFT tables (F2, F2T, G) ===============
__global__ void k_wt(const float* __restrict__ Wlin, const float* __restrict__ Wq,
                     const float* __restrict__ Wk, const float* __restrict__ Wadd,
                     u16* __restrict__ Wlin_b, u16* __restrict__ Wcat_b,
                     u16* __restrict__ F2, u16* __restrict__ F2T, u16* __restrict__ G) {
    int bid = blockIdx.x;
    if (bid < 640) {
        long idx = ((long)bid * 256 + threadIdx.x) * 8;
        const float* src;
        u16* dst;
        long off;
        if (idx < 524288) { src = Wlin; dst = Wlin_b + idx; off = idx; }
        else {
            long r = idx - 524288;
            dst = Wcat_b + r;
            if (r < 262144)      { src = Wq;   off = r; }
            else if (r < 524288) { src = Wk;   off = r - 262144; }
            else                 { src = Wadd; off = r - 524288; }
        }
        float4 a = *(const float4*)&src[off];
        float4 b = *(const float4*)&src[off + 4];
        ushort4 r0 = { f2bf(a.x), f2bf(a.y), f2bf(a.z), f2bf(a.w) };
        ushort4 r1 = { f2bf(b.x), f2bf(b.y), f2bf(b.z), f2bf(b.w) };
        *(ushort4*)dst = r0;
        *(ushort4*)(dst + 4) = r1;
    } else {
        int t = (bid - 640) * 256 + threadIdx.x;
        int which = t >> 14;
        int r = (t >> 7) & 127, c = t & 127;
        const float TWO_PI_128 = 6.283185307179586f / 128.f;
        if (which == 0) {
            int m = r & 63;
            int ph = (m * c) & 127;
            float ang = (float)ph * TWO_PI_128;
            float v = (r < 64) ? cosf(ang) : -sinf(ang);
            u16 h = f2bf(v);
            F2[r * 128 + c] = h;
            F2T[c * 128 + r] = h;
        } else {
            int m = c & 63;
            int ph = (m * r) & 127;
            float ang = (float)ph * TWO_PI_128;
            float cm = (m == 0) ? 1.f : 2.f;
            const float s = 1.f / (128.f * 512.f * 512.f);
            float v = (c < 64) ? cm * s * cosf(ang) : -cm * s * sinf(ang);
            G[r * 128 + c] = f2bf(v);
        }
    }
}

// =============== gemm_e: e = X(fp32) @ Wlin^T + b_lin; BM=32 BN=256 BK=128, grid 512 ===============
// XCD pairing: the two column-halves of one X row-slice land on the SAME XCD.
__global__ __launch_bounds__(256)
void k_gemm_e(const float* __restrict__ X, const u16* __restrict__ Wb,
              const float* __restrict__ bias, u16* __restrict__ eb) {
    __shared__ __align__(16) u16 As[32 * 128];    // 8 KB
    __shared__ __align__(16) u16 Bs[256 * 128];   // 64 KB
    const int tid = threadIdx.x, wv = tid >> 6, ln = tid & 63;
    const int L = blockIdx.x;                 // XCD = L & 7
    const int xcd = L & 7, j = L >> 3;
    const int m_idx = xcd * 32 + (j >> 1), xh = j & 1;
    const int m0 = m_idx * 32, n0 = xh * 256;
    const int arow = tid >> 3, acb = (tid & 7) * 16;
    f32x4 acc[2][4] = {};
    for (int k0 = 0; k0 < 1024; k0 += 128) {
        float4 xv[4];
        #pragma unroll
        for (int i = 0; i < 4; i++)   // X fp32 -> regs first
            xv[i] = *(const float4*)&X[(long)(m0 + arow) * 1024 + k0 + acb + i * 4];
        #pragma unroll
        for (int i = 0; i < 16; i++) {  // B: 256x128 bf16 via global_load_lds
            int c = i * 256 + tid;
            int row = c >> 4, kp = (c & 15) * 8;
            gl2lds16(Wb + (long)(n0 + row) * 1024 + k0 + kp, &Bs[(i * 256 + wv * 64) * 8]);
        }
        #pragma unroll
        for (int i = 0; i < 4; i++) {   // convert X -> As
            ushort4 r4 = { f2bf(xv[i].x), f2bf(xv[i].y), f2bf(xv[i].z), f2bf(xv[i].w) };
            *(ushort4*)&As[arow * 128 + acb + i * 4] = r4;
        }
        __syncthreads();
        #pragma unroll
        for (int kk = 0; kk < 4; kk++) {
            bf16x8 af[2], bfr[4];
            const int rr = ln & 15, ks = kk * 32 + (ln >> 4) * 8;
            #pragma unroll
            for (int m = 0; m < 2; m++) af[m] = *(const bf16x8*)&As[(m * 16 + rr) * 128 + ks];
            #pragma unroll
            for (int n = 0; n < 4; n++) bfr[n] = *(const bf16x8*)&Bs[(wv * 64 + n * 16 + rr) * 128 + ks];
            #pragma unroll
            for (int m = 0; m < 2; m++)
                #pragma unroll
                for (int n = 0; n < 4; n++)
                    acc[m][n] = __builtin_amdgcn_mfma_f32_16x16x32_bf16(af[m], bfr[n], acc[m][n], 0, 0, 0);
        }
        __syncthreads();
    }
    const int fq = ln >> 4, fr = ln & 15;
    #pragma unroll
    for (int m = 0; m < 2; m++)
        #pragma unroll
        for (int n = 0; n < 4; n++)
            #pragma unroll
            for (int j2 = 0; j2 < 4; j2++) {
                int row = m0 + m * 16 + fq * 4 + j2;
                int col = n0 + wv * 64 + n * 16 + fr;
                eb[(long)row * 512 + col] = f2bf(acc[m][n][j2] + bias[col]);
            }
}

// =============== gemm2: q,k natural + kT + add path; grid (12,64) ===============
__global__ __launch_bounds__(256)
void k_gemm_qka(const u16* __restrict__ A, const u16* __restrict__ B,
                u16* __restrict__ qg, u16* __restrict__ kg, u16* __restrict__ kT,
                u16* __restrict__ T, const float* __restrict__ bias) {
    __shared__ __align__(16) u16 As[128 * 64];
    __shared__ __align__(16) u16 Bs[128 * 64];
    const int tid = threadIdx.x, wv = tid >> 6, ln = tid & 63;
    int orig = blockIdx.y * 12 + blockIdx.x;
    int wg = (orig & 7) * 96 + (orig >> 3);
    const int by = wg / 12, bx = wg % 12;
    const u16* Ab = A + (long)(by * 128) * 512;
    const u16* Bb = B + (long)(bx * 128) * 512;
    f32x4 acc[4][4] = {};
    gemm_core128(Ab, 512, Bb, 512, 512, As, Bs, acc, tid);
    const int wm = (wv >> 1) * 64, wn = (wv & 1) * 64;
    const int fq = ln >> 4, fr = ln & 15;
    #pragma unroll
    for (int m = 0; m < 4; m++)
        #pragma unroll
        for (int n = 0; n < 4; n++) {
            int col = bx * 128 + wn + n * 16 + fr;
            int nn0 = wm + m * 16 + fq * 4;
            if (col < 512) {
                #pragma unroll
                for (int j = 0; j < 4; j++)
                    qg[(long)(by * 128 + nn0 + j) * 512 + col] = f2bf(acc[m][n][j]);
            } else if (col < 1024) {
                int e = col - 512;
                ushort4 pk = { f2bf(acc[m][n][0]), f2bf(acc[m][n][1]),
                               f2bf(acc[m][n][2]), f2bf(acc[m][n][3]) };
                *(ushort4*)&kT[(long)by * 65536 + (long)e * 128 + nn0] = pk;
                #pragma unroll
                for (int j = 0; j < 4; j++)
                    kg[(long)(by * 128 + nn0 + j) * 512 + e] = f2bf(acc[m][n][j]);
            } else {
                #pragma unroll
                for (int j = 0; j < 4; j++)
                    T[(long)(by * 128 + nn0 + j) * 512 + (col - 1024)] = f2bf(acc[m][n][j] + bias[col - 1024]);
            }
        }
}

// =============== k_M: M_b = q_b · k_b^T (K=512); grid 128 = (b, h) ===============
__global__ __launch_bounds__(256)
void k_M(const u16* __restrict__ qg, const u16* __restrict__ kg, u16* __restrict__ Mg) {
    __shared__ __align__(16) u16 As[64 * 64];
    __shared__ __align__(16) u16 Bs[128 * 64];
    const int tid = threadIdx.x, wv = tid >> 6, ln = tid & 63;
    const int b = blockIdx.x >> 1, h = blockIdx.x & 1;
    const u16* qb = qg + (long)b * 65536 + (long)(h * 64) * 512;
    const u16* kb = kg + (long)b * 65536;
    const int wm = (wv >> 1) * 32, wn = (wv & 1) * 64;
    f32x4 acc[2][4] = {};
    for (int k0 = 0; k0 < 512; k0 += 64) {
        #pragma unroll
        for (int i = 0; i < 2; i++) {
            int c = i * 256 + tid;
            int row = c >> 3, kp = (c & 7) * 8;
            gl2lds16(qb + (long)row * 512 + k0 + kp, &As[(i * 256 + wv * 64) * 8]);
        }
        #pragma unroll
        for (int i = 0; i < 4; i++) {
            int c = i * 256 + tid;
            int row = c >> 3, kp = (c & 7) * 8;
            gl2lds16(kb + (long)row * 512 + k0 + kp, &Bs[(i * 256 + wv * 64) * 8]);
        }
        __syncthreads();
        #pragma unroll
        for (int kk = 0; kk < 2; kk++) {
            bf16x8 af[2], bfr[4];
            const int rr = ln & 15, ks = kk * 32 + (ln >> 4) * 8;
            #pragma unroll
            for (int m = 0; m < 2; m++) af[m] = *(const bf16x8*)&As[(wm + m * 16 + rr) * 64 + ks];
            #pragma unroll
            for (int n = 0; n < 4; n++) bfr[n] = *(const bf16x8*)&Bs[(wn + n * 16 + rr) * 64 + ks];
            #pragma unroll
            for (int m = 0; m < 2; m++)
                #pragma unroll
                for (int n = 0; n < 4; n++)
                    acc[m][n] = __builtin_amdgcn_mfma_f32_16x16x32_bf16(af[m], bfr[n], acc[m][n], 0, 0, 0);
        }
        __syncthreads();
    }
    const int fq = ln >> 4, fr = ln & 15;
    #pragma unroll
    for (int m = 0; m < 2; m++)
        #pragma unroll
        for (int n = 0; n < 4; n++)
            #pragma unroll
            for (int j = 0; j < 4; j++) {
                int row = h * 64 + wm + m * 16 + fq * 4 + j;
                int col = wn + n * 16 + fr;
                Mg[(long)b * 16384 + (long)row * 128 + col] = f2bf(acc[m][n][j]);
            }
}

// =============== 128x128x128 MFMA from LDS(ld136)/global(ld128) operands ===============
template<bool AL, bool BL>
DEVFN void mm128(const u16* __restrict__ Ap, const u16* __restrict__ Bp,
                 f32x4 (&acc)[4][4], int wm, int wn, int rr, int kq) {
    #pragma unroll
    for (int s = 0; s < 4; s++) {
        int ks = s * 32 + kq;
        bf16x8 af[4], bfr[4];
        #pragma unroll
        for (int m = 0; m < 4; m++) {
            int r = wm + m * 16 + rr;
            af[m] = AL ? *(const bf16x8*)&Ap[r * 136 + ks] : *(const bf16x8*)&Ap[r * 128 + ks];
        }
        #pragma unroll
        for (int n = 0; n < 4; n++) {
            int r = wn + n * 16 + rr;
            bfr[n] = BL ? *(const bf16x8*)&Bp[r * 136 + ks] : *(const bf16x8*)&Bp[r * 128 + ks];
        }
        #pragma unroll
        for (int m = 0; m < 4; m++)
            #pragma unroll
            for (int n = 0; n < 4; n++)
                acc[m][n] = __builtin_amdgcn_mfma_f32_16x16x32_bf16(af[m], bfr[n], acc[m][n], 0, 0, 0);
    }
}

// =============== k_SH: S = F2·M·F2^T (fp32-reg tanh), H2 = G·Scat·F2; grid 64 ===============
__global__ __launch_bounds__(256)
void k_SH(const u16* __restrict__ Mg, const u16* __restrict__ F2g, const u16* __restrict__ F2Tg,
          const u16* __restrict__ Gg, u16* __restrict__ H2g) {
    __shared__ __align__(16) u16 L[53760];   // 3 slots x 17920 u16
    const int tid = threadIdx.x, wv = tid >> 6, ln = tid & 63;
    const int b = blockIdx.x;
    const int wm = (wv >> 1) * 64, wn = (wv & 1) * 64;
    const int rr = ln & 15, kq = (ln >> 4) * 8;
    const int fq = ln >> 4, fr = ln & 15;

    // load M natural -> S2 (ld136)
    u16* Mb = L + 35840;
    for (int c = tid; c < 2048; c += 256) {
        int row = c >> 4, col = (c & 15) * 8;
        *(bf16x8*)&Mb[row * 136 + col] = *(const bf16x8*)&Mg[(long)b * 16384 + (long)row * 128 + col];
    }
    __syncthreads();

    // phase B: P = M·F2^T, store P^T -> S0
    {
        f32x4 a2[4][4] = {};
        mm128<true, false>(Mb, F2g, a2, wm, wn, rr, kq);
        u16* Pt = L;
        #pragma unroll
        for (int m = 0; m < 4; m++)
            #pragma unroll
            for (int n = 0; n < 4; n++) {
                ushort4 pk = { f2bf(a2[m][n][0]), f2bf(a2[m][n][1]),
                               f2bf(a2[m][n][2]), f2bf(a2[m][n][3]) };
                *(ushort4*)&Pt[(wn + n * 16 + fr) * 136 + wm + m * 16 + fq * 4] = pk;
            }
    }
    __syncthreads();

    // phase C+D: S = F2·P in fp32 regs (quadrant-mapped frags), ctanh -> Sc (S1)
    {
        f32x4 a3[4][4] = {};
        const u16* Pt = L;
        #pragma unroll
        for (int s = 0; s < 4; s++) {
            int ks = s * 32 + kq;
            bf16x8 af[4], bfr[4];
            #pragma unroll
            for (int m = 0; m < 4; m++) {
                int r = (wv >> 1) * 32 + (m & 1) * 16 + (m >> 1) * 64 + rr;
                af[m] = *(const bf16x8*)&F2g[r * 128 + ks];
            }
            #pragma unroll
            for (int n = 0; n < 4; n++) {
                int r = (wv & 1) * 32 + (n & 1) * 16 + (n >> 1) * 64 + rr;
                bfr[n] = *(const bf16x8*)&Pt[r * 136 + ks];
            }
            #pragma unroll
            for (int m = 0; m < 4; m++)
                #pragma unroll
                for (int n = 0; n < 4; n++)
                    a3[m][n] = __builtin_amdgcn_mfma_f32_16x16x32_bf16(af[m], bfr[n], a3[m][n], 0, 0, 0);
        }
        u16* Sc = L + 17920;
        const int xb0 = (wv >> 1) * 32, yb0 = (wv & 1) * 32;
        #pragma unroll
        for (int m = 0; m < 2; m++)
            #pragma unroll
            for (int n = 0; n < 2; n++)
                #pragma unroll
                for (int j = 0; j < 4; j++) {
                    int x = xb0 + m * 16 + fq * 4 + j;
                    int y = yb0 + n * 16 + fr;
                    float c00 = a3[m][n][j];
                    float c01 = a3[m][n + 2][j];
                    float c10 = a3[m + 2][n][j];
                    float c11 = a3[m + 2][n + 2][j];
                    float re = c00 - c11, im = c01 + c10;
                    float tr, ti;
                    float x2 = 2.f * re, y2 = 2.f * im;
                    if (fabsf(x2) > 40.f) {
                        tr = (re > 0.f) ? 1.f : -1.f;
                        ti = 0.f;
                    } else {
                        float ex = expf(x2);
                        float sh = 0.5f * (ex - 1.f / ex), ch = 0.5f * (ex + 1.f / ex);
                        float sn, cs;
                        __sincosf(y2, &sn, &cs);
                        float d = ch + cs;
                        if (d > 1e-12f) {
                            tr = sh / d;
                            ti = sn / d;
                        } else {
                            tr = (re > 0.f) ? 1.f : ((re < 0.f) ? -1.f : 0.f);
                            ti = 0.f;
                        }
                    }
                    Sc[x * 136 + y] = f2bf(tr);
                    Sc[x * 136 + 64 + y] = f2bf(-ti);
                    Sc[(64 + x) * 136 + y] = f2bf(ti);
                    Sc[(64 + x) * 136 + 64 + y] = f2bf(tr);
                }
    }
    __syncthreads();

    // phase E: W = Scat·F2 (via F2T), store W^T -> S0
    {
        f32x4 a4[4][4] = {};
        mm128<true, false>(L + 17920, F2Tg, a4, wm, wn, rr, kq);
        u16* Wt = L;
        #pragma unroll
        for (int m = 0; m < 4; m++)
            #pragma unroll
            for (int n = 0; n < 4; n++) {
                ushort4 pk = { f2bf(a4[m][n][0]), f2bf(a4[m][n][1]),
                               f2bf(a4[m][n][2]), f2bf(a4[m][n][3]) };
                *(ushort4*)&Wt[(wn + n * 16 + fr) * 136 + wm + m * 16 + fq * 4] = pk;
            }
    }
    __syncthreads();

    // phase F: H2 = G·W -> global natural bf16
    {
        f32x4 a5[4][4] = {};
        mm128<false, true>(Gg, L, a5, wm, wn, rr, kq);
        #pragma unroll
        for (int m = 0; m < 4; m++)
            #pragma unroll
            for (int n = 0; n < 4; n++)
                #pragma unroll
                for (int j = 0; j < 4; j++)
                    H2g[(long)b * 16384 + (long)(wm + m * 16 + fq * 4 + j) * 128 + wn + n * 16 + fr]
                        = f2bf(a5[m][n][j]);
    }
}

// =============== k_T: T += H2·kT (contract n'); grid (4 e-tiles, 64 b) ===============
__global__ __launch_bounds__(256)
void k_T(const u16* __restrict__ H2g, const u16* __restrict__ kTg, u16* __restrict__ T) {
    __shared__ __align__(16) u16 Hs[128 * 136];
    __shared__ __align__(16) u16 Bs[128 * 136];
    const int tid = threadIdx.x, wv = tid >> 6, ln = tid & 63;
    const int et = blockIdx.x, b = blockIdx.y;
    const int wm = (wv >> 1) * 64, wn = (wv & 1) * 64;
    const int rr = ln & 15, kq = (ln >> 4) * 8;
    const int fq = ln >> 4, fr = ln & 15;

    for (int c = tid; c < 2048; c += 256) {
        int row = c >> 4, col = (c & 15) * 8;
        *(bf16x8*)&Hs[row * 136 + col] = *(const bf16x8*)&H2g[(long)b * 16384 + (long)row * 128 + col];
        *(bf16x8*)&Bs[row * 136 + col] =
            *(const bf16x8*)&kTg[(long)b * 65536 + (long)(et * 128 + row) * 128 + col];
    }
    __syncthreads();

    f32x4 acc[4][4] = {};
    mm128<true, true>(Hs, Bs, acc, wm, wn, rr, kq);
    #pragma unroll
    for (int m = 0; m < 4; m++)
        #pragma unroll
        for (int n = 0; n < 4; n++)
            #pragma unroll
            for (int j = 0; j < 4; j++) {
                int row = wm + m * 16 + fq * 4 + j;
                int col = et * 128 + wn + n * 16 + fr;
                long idx = ((long)b * 128 + row) * 512 + col;
                T[idx] = f2bf(bf2f(T[idx]) + acc[m][n][j]);
            }
}

// =============== final GEMM: part[ch][64][1024], 64 K-chunks, BK=128; grid (16,64) ===============
// XCD grouping: all 16 n-tiles of one k-chunk land on the same XCD (T chunk L2-resident).
__global__ __launch_bounds__(256)
void gemm_final(const u16* __restrict__ T, const float* __restrict__ Wf, float* __restrict__ part) {
    __shared__ __align__(16) u16 As[64 * 128];   // 16 KB
    __shared__ __align__(16) u16 Bs[64 * 128];   // 16 KB
    const int tid = threadIdx.x, wv = tid >> 6, ln = tid & 63;
    int d = blockIdx.y * 16 + blockIdx.x;              // 1024 blocks
    int xcd = d & 7, s = d >> 3;
    const int yk = xcd * 8 + (s & 7), xn = s >> 3;     // bijective: 8 yk per XCD, 16 xn each
    const int bn = xn * 64;
    const long kbase = (long)yk * 1024;
    const int wm = (wv >> 1) * 32, wn = (wv & 1) * 32;
    f32x4 acc[2][2] = {};
    for (int k0 = 0; k0 < 1024; k0 += 128) {
        float4 v[8];
        #pragma unroll
        for (int i = 0; i < 8; i++) {   // Wf fp32 -> regs first (8 in flight)
            int idx = i * 256 + tid;
            int row = idx >> 5, kp = (idx & 31) * 4;
            v[i] = *(const float4*)&Wf[(long)(bn + row) * 65536 + kbase + k0 + kp];
        }
        #pragma unroll
        for (int i = 0; i < 4; i++) {   // A via global_load_lds (stays in flight past vmcnt wait)
            int c = i * 256 + tid;
            int row = c >> 4, kp = (c & 15) * 8;
            gl2lds16(T + (long)row * 65536 + kbase + k0 + kp, &As[(i * 256 + wv * 64) * 8]);
        }
        #pragma unroll
        for (int i = 0; i < 8; i++) {
            int idx = i * 256 + tid;
            int row = idx >> 5, kp = (idx & 31) * 4;
            ushort4 r = { f2bf(v[i].x), f2bf(v[i].y), f2bf(v[i].z), f2bf(v[i].w) };
            *(ushort4*)&Bs[row * 128 + kp] = r;
        }
        __syncthreads();
        #pragma unroll
        for (int kk = 0; kk < 4; kk++) {
            bf16x8 af[2], bfr[2];
            const int rr = ln & 15, ks = kk * 32 + (ln >> 4) * 8;
            #pragma unroll
            for (int m = 0; m < 2; m++) af[m] = *(const bf16x8*)&As[(wm + m * 16 + rr) * 128 + ks];
            #pragma unroll
            for (int n = 0; n < 2; n++) bfr[n] = *(const bf16x8*)&Bs[(wn + n * 16 + rr) * 128 + ks];
            #pragma unroll
            for (int m = 0; m < 2; m++)
                #pragma unroll
                for (int n = 0; n < 2; n++)
                    acc[m][n] = __builtin_amdgcn_mfma_f32_16x16x32_bf16(af[m], bfr[n], acc[m][n], 0, 0, 0);
        }
        __syncthreads();
    }
    const int fq = ln >> 4, fr = ln & 15;
    #pragma unroll
    for (int m = 0; m < 2; m++)
        #pragma unroll
        for (int n = 0; n < 2; n++)
            #pragma unroll
            for (int j = 0; j < 4; j++) {
                int row = wm + m * 16 + fq * 4 + j;
                int col = bn + wn + n * 16 + fr;
                part[(long)yk * 65536 + (long)row * 1024 + col] = acc[m][n][j];
            }
}

__global__ void k_reduce(const float* __restrict__ part, const float* __restrict__ bias,
                         float* __restrict__ out) {
    int t = blockIdx.x * 256 + threadIdx.x;
    float s = bias[t & 1023];
    #pragma unroll 8
    for (int ch = 0; ch < 64; ch++) s += part[(long)ch * 65536 + t];
    out[t] = s;
}

// ---------------- workspace layout (bytes) ----------------
static const size_t MB = 1048576;
static const size_t OFF_T    = 0;        // [8192][512] bf16, 8MB
static const size_t OFF_Q    = 8 * MB;   // q natural 8MB (dead after k_M)
static const size_t OFF_K    = 16 * MB;  // k natural 8MB (dead after k_M)
static const size_t OFF_KT   = 24 * MB;  // kT [64][512][128] 8MB
static const size_t OFF_EB   = 32 * MB;  // e 8MB (dead after qka)
static const size_t OFF_MG   = 40 * MB;  // M [64][128][128] 2MB
static const size_t OFF_H2   = 42 * MB;  // H2 [64][128][128] 2MB
static const size_t OFF_WLIN = 44 * MB;
static const size_t OFF_WCAT = 45 * MB;
static const size_t OFF_F2   = 47 * MB;
static const size_t OFF_F2T  = 47 * MB + 32768;
static const size_t OFF_G    = 47 * MB + 65536;
static const size_t OFF_PART = 8 * MB;   // [64][65536] fp32 16MB (over q+k, dead)

extern "C" void kernel_launch(void* const* d_in, const int* in_sizes, int n_in,
                              void* d_out, int out_size, void* d_ws, size_t ws_size,
                              hipStream_t stream) {
    const float* X      = (const float*)d_in[0];
    const float* W_lin  = (const float*)d_in[1];
    const float* b_lin  = (const float*)d_in[2];
    const float* Wq     = (const float*)d_in[3];
    const float* Wk     = (const float*)d_in[4];
    const float* W_add  = (const float*)d_in[5];
    const float* b_add  = (const float*)d_in[6];
    const float* Wf     = (const float*)d_in[7];
    const float* b_fin  = (const float*)d_in[8];
    float* out = (float*)d_out;

    char* ws = (char*)d_ws;
    u16* T      = (u16*)(ws + OFF_T);
    u16* qg     = (u16*)(ws + OFF_Q);
    u16* kg     = (u16*)(ws + OFF_K);
    u16* kT     = (u16*)(ws + OFF_KT);
    u16* eb     = (u16*)(ws + OFF_EB);
    u16* Mg     = (u16*)(ws + OFF_MG);
    u16* H2g    = (u16*)(ws + OFF_H2);
    u16* Wlin_b = (u16*)(ws + OFF_WLIN);
    u16* Wcat_b = (u16*)(ws + OFF_WCAT);
    u16* F2     = (u16*)(ws + OFF_F2);
    u16* F2T    = (u16*)(ws + OFF_F2T);
    u16* G      = (u16*)(ws + OFF_G);
    float* part = (float*)(ws + OFF_PART);

    k_wt<<<768, 256, 0, stream>>>(W_lin, Wq, Wk, W_add, Wlin_b, Wcat_b, F2, F2T, G);
    k_gemm_e<<<512, 256, 0, stream>>>(X, Wlin_b, b_lin, eb);
    k_gemm_qka<<<dim3(12, 64), 256, 0, stream>>>(eb, Wcat_b, qg, kg, kT, T, b_add);
    k_M<<<128, 256, 0, stream>>>(qg, kg, Mg);
    k_SH<<<64, 256, 0, stream>>>(Mg, F2, F2T, G, H2g);
    k_T<<<dim3(4, 64), 256, 0, stream>>>(H2g, kT, T);
    gemm_final<<<dim3(16, 64), 256, 0, stream>>>(T, Wf, part);
    k_reduce<<<256, 256, 0, stream>>>(part, b_fin, out);
}

// Round 10
// 176.604 us; speedup vs baseline: 1.0234x; 1.0234x over previous
//
#include <hip/hip_runtime.h>

typedef float f32x4 __attribute__((ext_vector_type(4)));
typedef __bf16 bf16x8 __attribute__((ext_vector_type(8)));
typedef unsigned short u16;

#define DEVFN __device__ __forceinline__

DEVFN u16 f2bf(float f) {
    unsigned u = __builtin_bit_cast(unsigned, f);
    u += 0x7fffu + ((u >> 16) & 1u);
    return (u16)(u >> 16);
}
DEVFN float bf2f(u16 h) {
    unsigned u = ((unsigned)h) << 16;
    return __builtin_bit_cast(float, u);
}

DEVFN void gl2lds16(const void* g, void* l) {
    __builtin_amdgcn_global_load_lds(
        (const __attribute__((address_space(1))) void*)g,
        (__attribute__((address_space(3))) void*)l, 16, 0, 0);
}

// =============== shared 128x128 NT MFMA core (tile 128x128, K-step 64) ===============
DEVFN void gemm_core128(const u16* __restrict__ Ab, int lda,
                        const u16* __restrict__ Bb, int ldb, int K,
                        u16* As, u16* Bs, f32x4 (&acc)[4][4], int tid) {
    const int wv = tid >> 6, ln = tid & 63;
    const int wm = (wv >> 1) * 64, wn = (wv & 1) * 64;
    for (int k0 = 0; k0 < K; k0 += 64) {
        #pragma unroll
        for (int i = 0; i < 4; i++) {
            int c = i * 256 + tid;
            int row = c >> 3, kp = (c & 7) * 8;
            gl2lds16(Ab + (long)row * lda + k0 + kp, &As[(i * 256 + wv * 64) * 8]);
        }
        #pragma unroll
        for (int i = 0; i < 4; i++) {
            int c = i * 256 + tid;
            int row = c >> 3, kp = (c & 7) * 8;
            gl2lds16(Bb + (long)row * ldb + k0 + kp, &Bs[(i * 256 + wv * 64) * 8]);
        }
        __syncthreads();
        #pragma unroll
        for (int kk = 0; kk < 2; kk++) {
            bf16x8 af[4], bfr[4];
            const int rr = ln & 15, ks = kk * 32 + (ln >> 4) * 8;
            #pragma unroll
            for (int m = 0; m < 4; m++) af[m] = *(const bf16x8*)&As[(wm + m * 16 + rr) * 64 + ks];
            #pragma unroll
            for (int n = 0; n < 4; n++) bfr[n] = *(const bf16x8*)&Bs[(wn + n * 16 + rr) * 64 + ks];
            #pragma unroll
            for (int m = 0; m < 4; m++)
                #pragma unroll
                for (int n = 0; n < 4; n++)
                    acc[m][n] = __builtin_amdgcn_mfma_f32_16x16x32_bf16(af[m], bfr[n], acc[m][n], 0, 0, 0);
        }
        __syncthreads();
    }
}

// =============== weights convert + DFT tables (F2, F2T, G) + out-bias init ===============
__global__ void k_wt(const float* __restrict__ Wlin, const float* __restrict__ Wq,
                     const float* __restrict__ Wk, const float* __restrict__ Wadd,
                     u16* __restrict__ Wlin_b, u16* __restrict__ Wcat_b,
                     u16* __restrict__ F2, u16* __restrict__ F2T, u16* __restrict__ G,
                     const float* __restrict__ b_fin, float* __restrict__ out) {
    int bid = blockIdx.x;
    if (bid < 640) {
        long idx = ((long)bid * 256 + threadIdx.x) * 8;
        const float* src;
        u16* dst;
        long off;
        if (idx < 524288) { src = Wlin; dst = Wlin_b + idx; off = idx; }
        else {
            long r = idx - 524288;
            dst = Wcat_b + r;
            if (r < 262144)      { src = Wq;   off = r; }
            else if (r < 524288) { src = Wk;   off = r - 262144; }
            else                 { src = Wadd; off = r - 524288; }
        }
        float4 a = *(const float4*)&src[off];
        float4 b = *(const float4*)&src[off + 4];
        ushort4 r0 = { f2bf(a.x), f2bf(a.y), f2bf(a.z), f2bf(a.w) };
        ushort4 r1 = { f2bf(b.x), f2bf(b.y), f2bf(b.z), f2bf(b.w) };
        *(ushort4*)dst = r0;
        *(ushort4*)(dst + 4) = r1;
    } else if (bid < 768) {
        int t = (bid - 640) * 256 + threadIdx.x;
        int which = t >> 14;
        int r = (t >> 7) & 127, c = t & 127;
        const float TWO_PI_128 = 6.283185307179586f / 128.f;
        if (which == 0) {
            int m = r & 63;
            int ph = (m * c) & 127;
            float ang = (float)ph * TWO_PI_128;
            float v = (r < 64) ? cosf(ang) : -sinf(ang);
            u16 h = f2bf(v);
            F2[r * 128 + c] = h;
            F2T[c * 128 + r] = h;
        } else {
            int m = c & 63;
            int ph = (m * r) & 127;
            float ang = (float)ph * TWO_PI_128;
            float cm = (m == 0) ? 1.f : 2.f;
            const float s = 1.f / (128.f * 512.f * 512.f);
            float v = (c < 64) ? cm * s * cosf(ang) : -cm * s * sinf(ang);
            G[r * 128 + c] = f2bf(v);
        }
    } else {
        int t = (bid - 768) * 256 + threadIdx.x;   // < 65536: out = bias (re-init every call)
        out[t] = b_fin[t & 1023];
    }
}

// =============== gemm_e: e = X(fp32) @ Wlin^T + b_lin; BM=32 BN=256, grid 512 ===============
// XCD pairing: the two column-halves of one X row-slice land on the SAME XCD.
__global__ __launch_bounds__(256)
void k_gemm_e(const float* __restrict__ X, const u16* __restrict__ Wb,
              const float* __restrict__ bias, u16* __restrict__ eb) {
    __shared__ __align__(16) u16 As[32 * 64];
    __shared__ __align__(16) u16 Bs[256 * 64];
    const int tid = threadIdx.x, wv = tid >> 6, ln = tid & 63;
    const int L = blockIdx.x;                 // XCD = L & 7
    const int xcd = L & 7, j = L >> 3;
    const int m_idx = xcd * 32 + (j >> 1), xh = j & 1;
    const int m0 = m_idx * 32, n0 = xh * 256;
    f32x4 acc[2][4] = {};
    for (int k0 = 0; k0 < 1024; k0 += 64) {
        #pragma unroll
        for (int i = 0; i < 8; i++) {
            int c = i * 256 + tid;
            int row = c >> 3, kp = (c & 7) * 8;
            gl2lds16(Wb + (long)(n0 + row) * 1024 + k0 + kp, &Bs[(i * 256 + wv * 64) * 8]);
        }
        {
            int row = tid >> 3, colg = (tid & 7) * 8;
            const float4* src = (const float4*)&X[(long)(m0 + row) * 1024 + k0 + colg];
            float4 a = src[0], b = src[1];
            ushort4 r0 = { f2bf(a.x), f2bf(a.y), f2bf(a.z), f2bf(a.w) };
            ushort4 r1 = { f2bf(b.x), f2bf(b.y), f2bf(b.z), f2bf(b.w) };
            *(ushort4*)&As[row * 64 + colg] = r0;
            *(ushort4*)&As[row * 64 + colg + 4] = r1;
        }
        __syncthreads();
        #pragma unroll
        for (int kk = 0; kk < 2; kk++) {
            bf16x8 af[2], bfr[4];
            const int rr = ln & 15, ks = kk * 32 + (ln >> 4) * 8;
            #pragma unroll
            for (int m = 0; m < 2; m++) af[m] = *(const bf16x8*)&As[(m * 16 + rr) * 64 + ks];
            #pragma unroll
            for (int n = 0; n < 4; n++) bfr[n] = *(const bf16x8*)&Bs[(wv * 64 + n * 16 + rr) * 64 + ks];
            #pragma unroll
            for (int m = 0; m < 2; m++)
                #pragma unroll
                for (int n = 0; n < 4; n++)
                    acc[m][n] = __builtin_amdgcn_mfma_f32_16x16x32_bf16(af[m], bfr[n], acc[m][n], 0, 0, 0);
        }
        __syncthreads();
    }
    const int fq = ln >> 4, fr = ln & 15;
    #pragma unroll
    for (int m = 0; m < 2; m++)
        #pragma unroll
        for (int n = 0; n < 4; n++)
            #pragma unroll
            for (int j2 = 0; j2 < 4; j2++) {
                int row = m0 + m * 16 + fq * 4 + j2;
                int col = n0 + wv * 64 + n * 16 + fr;
                eb[(long)row * 512 + col] = f2bf(acc[m][n][j2] + bias[col]);
            }
}

// =============== gemm2: q,k natural + kT + add path; grid (12,64) ===============
__global__ __launch_bounds__(256)
void k_gemm_qka(const u16* __restrict__ A, const u16* __restrict__ B,
                u16* __restrict__ qg, u16* __restrict__ kg, u16* __restrict__ kT,
                u16* __restrict__ T, const float* __restrict__ bias) {
    __shared__ __align__(16) u16 As[128 * 64];
    __shared__ __align__(16) u16 Bs[128 * 64];
    const int tid = threadIdx.x, wv = tid >> 6, ln = tid & 63;
    int orig = blockIdx.y * 12 + blockIdx.x;
    int wg = (orig & 7) * 96 + (orig >> 3);
    const int by = wg / 12, bx = wg % 12;
    const u16* Ab = A + (long)(by * 128) * 512;
    const u16* Bb = B + (long)(bx * 128) * 512;
    f32x4 acc[4][4] = {};
    gemm_core128(Ab, 512, Bb, 512, 512, As, Bs, acc, tid);
    const int wm = (wv >> 1) * 64, wn = (wv & 1) * 64;
    const int fq = ln >> 4, fr = ln & 15;
    #pragma unroll
    for (int m = 0; m < 4; m++)
        #pragma unroll
        for (int n = 0; n < 4; n++) {
            int col = bx * 128 + wn + n * 16 + fr;
            int nn0 = wm + m * 16 + fq * 4;
            if (col < 512) {
                #pragma unroll
                for (int j = 0; j < 4; j++)
                    qg[(long)(by * 128 + nn0 + j) * 512 + col] = f2bf(acc[m][n][j]);
            } else if (col < 1024) {
                int e = col - 512;
                ushort4 pk = { f2bf(acc[m][n][0]), f2bf(acc[m][n][1]),
                               f2bf(acc[m][n][2]), f2bf(acc[m][n][3]) };
                *(ushort4*)&kT[(long)by * 65536 + (long)e * 128 + nn0] = pk;
                #pragma unroll
                for (int j = 0; j < 4; j++)
                    kg[(long)(by * 128 + nn0 + j) * 512 + e] = f2bf(acc[m][n][j]);
            } else {
                #pragma unroll
                for (int j = 0; j < 4; j++)
                    T[(long)(by * 128 + nn0 + j) * 512 + (col - 1024)] = f2bf(acc[m][n][j] + bias[col - 1024]);
            }
        }
}

// =============== k_M: M_b = q_b · k_b^T (K=512); grid 128 = (b, h) ===============
__global__ __launch_bounds__(256)
void k_M(const u16* __restrict__ qg, const u16* __restrict__ kg, u16* __restrict__ Mg) {
    __shared__ __align__(16) u16 As[64 * 64];
    __shared__ __align__(16) u16 Bs[128 * 64];
    const int tid = threadIdx.x, wv = tid >> 6, ln = tid & 63;
    const int b = blockIdx.x >> 1, h = blockIdx.x & 1;
    const u16* qb = qg + (long)b * 65536 + (long)(h * 64) * 512;
    const u16* kb = kg + (long)b * 65536;
    const int wm = (wv >> 1) * 32, wn = (wv & 1) * 64;
    f32x4 acc[2][4] = {};
    for (int k0 = 0; k0 < 512; k0 += 64) {
        #pragma unroll
        for (int i = 0; i < 2; i++) {
            int c = i * 256 + tid;
            int row = c >> 3, kp = (c & 7) * 8;
            gl2lds16(qb + (long)row * 512 + k0 + kp, &As[(i * 256 + wv * 64) * 8]);
        }
        #pragma unroll
        for (int i = 0; i < 4; i++) {
            int c = i * 256 + tid;
            int row = c >> 3, kp = (c & 7) * 8;
            gl2lds16(kb + (long)row * 512 + k0 + kp, &Bs[(i * 256 + wv * 64) * 8]);
        }
        __syncthreads();
        #pragma unroll
        for (int kk = 0; kk < 2; kk++) {
            bf16x8 af[2], bfr[4];
            const int rr = ln & 15, ks = kk * 32 + (ln >> 4) * 8;
            #pragma unroll
            for (int m = 0; m < 2; m++) af[m] = *(const bf16x8*)&As[(wm + m * 16 + rr) * 64 + ks];
            #pragma unroll
            for (int n = 0; n < 4; n++) bfr[n] = *(const bf16x8*)&Bs[(wn + n * 16 + rr) * 64 + ks];
            #pragma unroll
            for (int m = 0; m < 2; m++)
                #pragma unroll
                for (int n = 0; n < 4; n++)
                    acc[m][n] = __builtin_amdgcn_mfma_f32_16x16x32_bf16(af[m], bfr[n], acc[m][n], 0, 0, 0);
        }
        __syncthreads();
    }
    const int fq = ln >> 4, fr = ln & 15;
    #pragma unroll
    for (int m = 0; m < 2; m++)
        #pragma unroll
        for (int n = 0; n < 4; n++)
            #pragma unroll
            for (int j = 0; j < 4; j++) {
                int row = h * 64 + wm + m * 16 + fq * 4 + j;
                int col = wn + n * 16 + fr;
                Mg[(long)b * 16384 + (long)row * 128 + col] = f2bf(acc[m][n][j]);
            }
}

// =============== 128x128x128 MFMA from LDS(ld136)/global(ld128) operands ===============
template<bool AL, bool BL>
DEVFN void mm128(const u16* __restrict__ Ap, const u16* __restrict__ Bp,
                 f32x4 (&acc)[4][4], int wm, int wn, int rr, int kq) {
    #pragma unroll
    for (int s = 0; s < 4; s++) {
        int ks = s * 32 + kq;
        bf16x8 af[4], bfr[4];
        #pragma unroll
        for (int m = 0; m < 4; m++) {
            int r = wm + m * 16 + rr;
            af[m] = AL ? *(const bf16x8*)&Ap[r * 136 + ks] : *(const bf16x8*)&Ap[r * 128 + ks];
        }
        #pragma unroll
        for (int n = 0; n < 4; n++) {
            int r = wn + n * 16 + rr;
            bfr[n] = BL ? *(const bf16x8*)&Bp[r * 136 + ks] : *(const bf16x8*)&Bp[r * 128 + ks];
        }
        #pragma unroll
        for (int m = 0; m < 4; m++)
            #pragma unroll
            for (int n = 0; n < 4; n++)
                acc[m][n] = __builtin_amdgcn_mfma_f32_16x16x32_bf16(af[m], bfr[n], acc[m][n], 0, 0, 0);
    }
}

// =============== k_SH: S = F2·M·F2^T (fp32-reg tanh), H2 = G·Scat·F2; grid 64 ===============
__global__ __launch_bounds__(256)
void k_SH(const u16* __restrict__ Mg, const u16* __restrict__ F2g, const u16* __restrict__ F2Tg,
          const u16* __restrict__ Gg, u16* __restrict__ H2g) {
    __shared__ __align__(16) u16 L[53760];   // 3 slots x 17920 u16
    const int tid = threadIdx.x, wv = tid >> 6, ln = tid & 63;
    const int b = blockIdx.x;
    const int wm = (wv >> 1) * 64, wn = (wv & 1) * 64;
    const int rr = ln & 15, kq = (ln >> 4) * 8;
    const int fq = ln >> 4, fr = ln & 15;

    // load M natural -> S2 (ld136)
    u16* Mb = L + 35840;
    for (int c = tid; c < 2048; c += 256) {
        int row = c >> 4, col = (c & 15) * 8;
        *(bf16x8*)&Mb[row * 136 + col] = *(const bf16x8*)&Mg[(long)b * 16384 + (long)row * 128 + col];
    }
    __syncthreads();

    // phase B: P = M·F2^T, store P^T -> S0
    {
        f32x4 a2[4][4] = {};
        mm128<true, false>(Mb, F2g, a2, wm, wn, rr, kq);
        u16* Pt = L;
        #pragma unroll
        for (int m = 0; m < 4; m++)
            #pragma unroll
            for (int n = 0; n < 4; n++) {
                ushort4 pk = { f2bf(a2[m][n][0]), f2bf(a2[m][n][1]),
                               f2bf(a2[m][n][2]), f2bf(a2[m][n][3]) };
                *(ushort4*)&Pt[(wn + n * 16 + fr) * 136 + wm + m * 16 + fq * 4] = pk;
            }
    }
    __syncthreads();

    // phase C+D: S = F2·P in fp32 regs (quadrant-mapped frags), ctanh -> Sc (S1)
    {
        f32x4 a3[4][4] = {};
        const u16* Pt = L;
        #pragma unroll
        for (int s = 0; s < 4; s++) {
            int ks = s * 32 + kq;
            bf16x8 af[4], bfr[4];
            #pragma unroll
            for (int m = 0; m < 4; m++) {
                int r = (wv >> 1) * 32 + (m & 1) * 16 + (m >> 1) * 64 + rr;
                af[m] = *(const bf16x8*)&F2g[r * 128 + ks];
            }
            #pragma unroll
            for (int n = 0; n < 4; n++) {
                int r = (wv & 1) * 32 + (n & 1) * 16 + (n >> 1) * 64 + rr;
                bfr[n] = *(const bf16x8*)&Pt[r * 136 + ks];
            }
            #pragma unroll
            for (int m = 0; m < 4; m++)
                #pragma unroll
                for (int n = 0; n < 4; n++)
                    a3[m][n] = __builtin_amdgcn_mfma_f32_16x16x32_bf16(af[m], bfr[n], a3[m][n], 0, 0, 0);
        }
        u16* Sc = L + 17920;
        const int xb0 = (wv >> 1) * 32, yb0 = (wv & 1) * 32;
        #pragma unroll
        for (int m = 0; m < 2; m++)
            #pragma unroll
            for (int n = 0; n < 2; n++)
                #pragma unroll
                for (int j = 0; j < 4; j++) {
                    int x = xb0 + m * 16 + fq * 4 + j;
                    int y = yb0 + n * 16 + fr;
                    float c00 = a3[m][n][j];
                    float c01 = a3[m][n + 2][j];
                    float c10 = a3[m + 2][n][j];
                    float c11 = a3[m + 2][n + 2][j];
                    float re = c00 - c11, im = c01 + c10;
                    float tr, ti;
                    float x2 = 2.f * re, y2 = 2.f * im;
                    if (fabsf(x2) > 40.f) {
                        tr = (re > 0.f) ? 1.f : -1.f;
                        ti = 0.f;
                    } else {
                        float ex = expf(x2);
                        float sh = 0.5f * (ex - 1.f / ex), ch = 0.5f * (ex + 1.f / ex);
                        float sn, cs;
                        __sincosf(y2, &sn, &cs);
                        float d = ch + cs;
                        if (d > 1e-12f) {
                            tr = sh / d;
                            ti = sn / d;
                        } else {
                            tr = (re > 0.f) ? 1.f : ((re < 0.f) ? -1.f : 0.f);
                            ti = 0.f;
                        }
                    }
                    Sc[x * 136 + y] = f2bf(tr);
                    Sc[x * 136 + 64 + y] = f2bf(-ti);
                    Sc[(64 + x) * 136 + y] = f2bf(ti);
                    Sc[(64 + x) * 136 + 64 + y] = f2bf(tr);
                }
    }
    __syncthreads();

    // phase E: W = Scat·F2 (via F2T), store W^T -> S0
    {
        f32x4 a4[4][4] = {};
        mm128<true, false>(L + 17920, F2Tg, a4, wm, wn, rr, kq);
        u16* Wt = L;
        #pragma unroll
        for (int m = 0; m < 4; m++)
            #pragma unroll
            for (int n = 0; n < 4; n++) {
                ushort4 pk = { f2bf(a4[m][n][0]), f2bf(a4[m][n][1]),
                               f2bf(a4[m][n][2]), f2bf(a4[m][n][3]) };
                *(ushort4*)&Wt[(wn + n * 16 + fr) * 136 + wm + m * 16 + fq * 4] = pk;
            }
    }
    __syncthreads();

    // phase F: H2 = G·W -> global natural bf16
    {
        f32x4 a5[4][4] = {};
        mm128<false, true>(Gg, L, a5, wm, wn, rr, kq);
        #pragma unroll
        for (int m = 0; m < 4; m++)
            #pragma unroll
            for (int n = 0; n < 4; n++)
                #pragma unroll
                for (int j = 0; j < 4; j++)
                    H2g[(long)b * 16384 + (long)(wm + m * 16 + fq * 4 + j) * 128 + wn + n * 16 + fr]
                        = f2bf(a5[m][n][j]);
    }
}

// =============== k_T: T += H2·kT (contract n'); grid (4 e-tiles, 64 b) ===============
__global__ __launch_bounds__(256)
void k_T(const u16* __restrict__ H2g, const u16* __restrict__ kTg, u16* __restrict__ T) {
    __shared__ __align__(16) u16 Hs[128 * 136];
    __shared__ __align__(16) u16 Bs[128 * 136];
    const int tid = threadIdx.x, wv = tid >> 6, ln = tid & 63;
    const int et = blockIdx.x, b = blockIdx.y;
    const int wm = (wv >> 1) * 64, wn = (wv & 1) * 64;
    const int rr = ln & 15, kq = (ln >> 4) * 8;
    const int fq = ln >> 4, fr = ln & 15;

    for (int c = tid; c < 2048; c += 256) {
        int row = c >> 4, col = (c & 15) * 8;
        *(bf16x8*)&Hs[row * 136 + col] = *(const bf16x8*)&H2g[(long)b * 16384 + (long)row * 128 + col];
        *(bf16x8*)&Bs[row * 136 + col] =
            *(const bf16x8*)&kTg[(long)b * 65536 + (long)(et * 128 + row) * 128 + col];
    }
    __syncthreads();

    f32x4 acc[4][4] = {};
    mm128<true, true>(Hs, Bs, acc, wm, wn, rr, kq);
    #pragma unroll
    for (int m = 0; m < 4; m++)
        #pragma unroll
        for (int n = 0; n < 4; n++)
            #pragma unroll
            for (int j = 0; j < 4; j++) {
                int row = wm + m * 16 + fq * 4 + j;
                int col = et * 128 + wn + n * 16 + fr;
                long idx = ((long)b * 128 + row) * 512 + col;
                T[idx] = f2bf(bf2f(T[idx]) + acc[m][n][j]);
            }
}

// =============== final GEMM: out += T[64,1024ch] @ Wf^T (atomic split-K 64); grid (16,64) ===============
// XCD grouping: all 16 n-tiles of one k-chunk land on the same XCD (T chunk L2-resident).
__global__ __launch_bounds__(256)
void gemm_final(const u16* __restrict__ T, const float* __restrict__ Wf, float* __restrict__ out) {
    __shared__ __align__(16) u16 As[64 * 64];
    __shared__ __align__(16) u16 Bs[64 * 64];
    const int tid = threadIdx.x, wv = tid >> 6, ln = tid & 63;
    int d = blockIdx.y * 16 + blockIdx.x;              // 1024 blocks
    int xcd = d & 7, s = d >> 3;
    const int yk = xcd * 8 + (s & 7), xn = s >> 3;     // bijective: 8 yk per XCD, 16 xn each
    const int bn = xn * 64;
    const long kbase = (long)yk * 1024;
    const int wm = (wv >> 1) * 32, wn = (wv & 1) * 32;
    f32x4 acc[2][2] = {};
    for (int k0 = 0; k0 < 1024; k0 += 64) {
        float4 v[4];
        #pragma unroll
        for (int i = 0; i < 4; i++) {
            int idx = i * 256 + tid;
            int row = idx >> 4, kp = (idx & 15) * 4;
            v[i] = *(const float4*)&Wf[(long)(bn + row) * 65536 + kbase + k0 + kp];
        }
        #pragma unroll
        for (int i = 0; i < 2; i++) {
            int c = i * 256 + tid;
            int row = c >> 3, kp = (c & 7) * 8;
            gl2lds16(T + (long)row * 65536 + kbase + k0 + kp, &As[(i * 256 + wv * 64) * 8]);
        }
        #pragma unroll
        for (int i = 0; i < 4; i++) {
            int idx = i * 256 + tid;
            int row = idx >> 4, kp = (idx & 15) * 4;
            ushort4 r = { f2bf(v[i].x), f2bf(v[i].y), f2bf(v[i].z), f2bf(v[i].w) };
            *(ushort4*)&Bs[row * 64 + kp] = r;
        }
        __syncthreads();
        #pragma unroll
        for (int kk = 0; kk < 2; kk++) {
            bf16x8 af[2], bfr[2];
            const int rr = ln & 15, ks = kk * 32 + (ln >> 4) * 8;
            #pragma unroll
            for (int m = 0; m < 2; m++) af[m] = *(const bf16x8*)&As[(wm + m * 16 + rr) * 64 + ks];
            #pragma unroll
            for (int n = 0; n < 2; n++) bfr[n] = *(const bf16x8*)&Bs[(wn + n * 16 + rr) * 64 + ks];
            #pragma unroll
            for (int m = 0; m < 2; m++)
                #pragma unroll
                for (int n = 0; n < 2; n++)
                    acc[m][n] = __builtin_amdgcn_mfma_f32_16x16x32_bf16(af[m], bfr[n], acc[m][n], 0, 0, 0);
        }
        __syncthreads();
    }
    const int fq = ln >> 4, fr = ln & 15;
    #pragma unroll
    for (int m = 0; m < 2; m++)
        #pragma unroll
        for (int n = 0; n < 2; n++)
            #pragma unroll
            for (int j = 0; j < 4; j++) {
                int row = wm + m * 16 + fq * 4 + j;
                int col = bn + wn + n * 16 + fr;
                atomicAdd(&out[(long)row * 1024 + col], acc[m][n][j]);
            }
}

// ---------------- workspace layout (bytes) ----------------
static const size_t MB = 1048576;
static const size_t OFF_T    = 0;        // [8192][512] bf16, 8MB
static const size_t OFF_Q    = 8 * MB;   // q natural 8MB (dead after k_M)
static const size_t OFF_K    = 16 * MB;  // k natural 8MB (dead after k_M)
static const size_t OFF_KT   = 24 * MB;  // kT [64][512][128] 8MB
static const size_t OFF_EB   = 32 * MB;  // e 8MB (dead after qka)
static const size_t OFF_MG   = 40 * MB;  // M [64][128][128] 2MB
static const size_t OFF_H2   = 42 * MB;  // H2 [64][128][128] 2MB
static const size_t OFF_WLIN = 44 * MB;
static const size_t OFF_WCAT = 45 * MB;
static const size_t OFF_F2   = 47 * MB;
static const size_t OFF_F2T  = 47 * MB + 32768;
static const size_t OFF_G    = 47 * MB + 65536;

extern "C" void kernel_launch(void* const* d_in, const int* in_sizes, int n_in,
                              void* d_out, int out_size, void* d_ws, size_t ws_size,
                              hipStream_t stream) {
    const float* X      = (const float*)d_in[0];
    const float* W_lin  = (const float*)d_in[1];
    const float* b_lin  = (const float*)d_in[2];
    const float* Wq     = (const float*)d_in[3];
    const float* Wk     = (const float*)d_in[4];
    const float* W_add  = (const float*)d_in[5];
    const float* b_add  = (const float*)d_in[6];
    const float* Wf     = (const float*)d_in[7];
    const float* b_fin  = (const float*)d_in[8];
    float* out = (float*)d_out;

    char* ws = (char*)d_ws;
    u16* T      = (u16*)(ws + OFF_T);
    u16* qg     = (u16*)(ws + OFF_Q);
    u16* kg     = (u16*)(ws + OFF_K);
    u16* kT     = (u16*)(ws + OFF_KT);
    u16* eb     = (u16*)(ws + OFF_EB);
    u16* Mg     = (u16*)(ws + OFF_MG);
    u16* H2g    = (u16*)(ws + OFF_H2);
    u16* Wlin_b = (u16*)(ws + OFF_WLIN);
    u16* Wcat_b = (u16*)(ws + OFF_WCAT);
    u16* F2     = (u16*)(ws + OFF_F2);
    u16* F2T    = (u16*)(ws + OFF_F2T);
    u16* G      = (u16*)(ws + OFF_G);

    k_wt<<<1024, 256, 0, stream>>>(W_lin, Wq, Wk, W_add, Wlin_b, Wcat_b, F2, F2T, G, b_fin, out);
    k_gemm_e<<<512, 256, 0, stream>>>(X, Wlin_b, b_lin, eb);
    k_gemm_qka<<<dim3(12, 64), 256, 0, stream>>>(eb, Wcat_b, qg, kg, kT, T, b_add);
    k_M<<<128, 256, 0, stream>>>(qg, kg, Mg);
    k_SH<<<64, 256, 0, stream>>>(Mg, F2, F2T, G, H2g);
    k_T<<<dim3(4, 64), 256, 0, stream>>>(H2g, kT, T);
    gemm_final<<<dim3(16, 64), 256, 0, stream>>>(T, Wf, out);
}